// Round 5
// baseline (466.880 us; speedup 1.0000x reference)
//
#include <hip/hip_runtime.h>
#include <hip/hip_cooperative_groups.h>

// Bilateral 5x5, 3 chained passes. [32,1,512,512] fp32, replicate padding,
// w = exp2(dr^2*nax + dc^2*nay + d^2*ncr).
//
// Round-13: ONE COOPERATIVE LAUNCH. Round-12 (direct-global, no LDS, no
// barrier) dropped all three passes below the profiler cutoff; the bench
// floor decomposes as 42us ws-poison fill + ~19us harness-fixed + ~69us
// for {3 passes + 2 launch gaps}. Passes model at ~11us each (HBM round
// trip 10.6us, VALU floor ~7us) => ~35us of the 69 is launch overhead and
// inter-dispatch serialization (~10us/launch per rocprof.md). This round
// launches ONE cooperative kernel (grid = co-residency capacity from the
// occupancy query, grid-strided over 8192 tiles/pass) with
// __threadfence() + grid.sync() between passes. Same bilat_px4 body ->
// bit-identical output. Fallback 1: coop enqueue fails -> proven 3-launch
// path. Fallback 2: no ws -> fused single kernel.
//
// Pruning (round 3): taps with spatial log2-weight < TH2 skipped via
// block-uniform branches -> effective 3x3 for sigma=0.5 (8 exps/px).
// Generic 5x5 path kept for large sigma (cold).

namespace cg = cooperative_groups;

typedef float v2f __attribute__((ext_vector_type(2)));

#define EXP2(x) __builtin_amdgcn_exp2f(x)
#define RCP(x)  __builtin_amdgcn_rcpf(x)
#define TH2 (-10.0f)

// ---------------- shared tap core (validated rounds 8-12) ----------------

// One packed tap-pair: 5 pk ops + 2 exp for 2 pixels.
__device__ __forceinline__ void tap_pair(v2f nb, v2f ce, v2f& nu, v2f& de,
                                         float b, v2f ncr2)
{
    v2f d  = nb - ce;                                   // pk_add
    v2f tt = __builtin_elementwise_fma(d * d, ncr2,
                                       (v2f){b, b});    // pk_mul+pk_fma
    v2f w  = {EXP2(tt.x), EXP2(tt.y)};
    nu = __builtin_elementwise_fma(w, nb, nu);          // pk_fma
    de += w;                                            // pk_add
}

// All horizontal taps of one window row against centers c01/c23.
__device__ __forceinline__ void row_taps(const float* w6, v2f c01, v2f c23,
                                         v2f& n01, v2f& n23, v2f& d01, v2f& d23,
                                         float bm, float b0, float bp,
                                         bool skip0, v2f ncr2)
{
    tap_pair((v2f){w6[0], w6[1]}, c01, n01, d01, bm, ncr2);   // dc=-1
    tap_pair((v2f){w6[2], w6[3]}, c23, n23, d23, bm, ncr2);
    if (!skip0) {
        tap_pair((v2f){w6[1], w6[2]}, c01, n01, d01, b0, ncr2); // dc=0
        tap_pair((v2f){w6[3], w6[4]}, c23, n23, d23, b0, ncr2);
    }
    tap_pair((v2f){w6[2], w6[3]}, c01, n01, d01, bp, ncr2);   // dc=+1
    tap_pair((v2f){w6[4], w6[5]}, c23, n23, d23, bp, ncr2);
}

// Packed 3x3 bilateral core for 4 px: 16 tap-pairs = 80 pk ops + 32 exp.
__device__ __forceinline__ float4 core3x3(const float* wm, const float* wc,
                                          const float* wp,
                                          float nax, float nay, v2f ncr2)
{
    v2f c01 = {wc[1], wc[2]}, c23 = {wc[3], wc[4]};
    v2f n01 = c01, n23 = c23;               // center tap, w == 1
    v2f d01 = {1.f, 1.f}, d23 = {1.f, 1.f};
    const float bd = nax + nay;
    row_taps(wc, c01, c23, n01, n23, d01, d23, nay, 0.0f, nay, true,  ncr2);
    row_taps(wm, c01, c23, n01, n23, d01, d23, bd,  nax,  bd,  false, ncr2);
    row_taps(wp, c01, c23, n01, n23, d01, d23, bd,  nax,  bd,  false, ncr2);
    float4 o;
    o.x = n01.x * RCP(d01.x);
    o.y = n01.y * RCP(d01.y);
    o.z = n23.x * RCP(d23.x);
    o.w = n23.y * RCP(d23.y);
    return o;
}

// 6-wide window row: aligned quad [gx..gx+3] + clamped scalars gx-1, gx+4.
__device__ __forceinline__ void ld6(const float* __restrict__ rowp, int gx,
                                    int W, float* w6)
{
    const float4 M = *(const float4*)(rowp + gx);       // 16B aligned
    const float  lw = rowp[max(gx - 1, 0)];             // branchless clamp
    const float  rx = rowp[min(gx + 4, W - 1)];
    w6[0] = lw;  w6[1] = M.x; w6[2] = M.y; w6[3] = M.z; w6[4] = M.w;
    w6[5] = rx;
}

// One 4-px bilateral unit at (gy, gx..gx+3), direct global -> global.
__device__ __forceinline__ void bilat_px4(const float* __restrict__ img,
                                          float* __restrict__ outp,
                                          int gx, int gy, int H, int W,
                                          float ncr, float nax, float nay,
                                          bool prune, v2f ncr2)
{
    float* op = outp + (size_t)gy * W + gx;

    if (prune) {
        // rows gy-1, gy, gy+1 (replicate-clamped row bases, branchless)
        const float* rm = img + (size_t)max(gy - 1, 0)     * W;
        const float* rc = img + (size_t)gy                 * W;
        const float* rp = img + (size_t)min(gy + 1, H - 1) * W;
        float wm[6], wc[6], wp[6];
        ld6(rm, gx, W, wm);                 // 9 independent loads total
        ld6(rc, gx, W, wc);
        ld6(rp, gx, W, wp);
        *(float4*)op = core3x3(wm, wc, wp, nax, nay, ncr2);
    } else {
        // ---- generic 5x5, streaming per row (cold path) ----
        const float4 C = *(const float4*)(img + (size_t)gy * W + gx);
        float cen[4] = {C.x, C.y, C.z, C.w};
        float num[4] = {C.x, C.y, C.z, C.w};
        float den[4] = {1.f, 1.f, 1.f, 1.f};
        #pragma unroll
        for (int dr = -2; dr <= 2; ++dr) {
            const float ra = (float)(dr * dr) * nax;
            const float rbest = dr ? ra : nay;
            if (rbest < TH2) continue;
            const float* rp2 = img + (size_t)min(max(gy + dr, 0), H - 1) * W;
            const float4 Mq = *(const float4*)(rp2 + gx);
            const float w8[8] = {
                rp2[max(gx - 2, 0)], rp2[max(gx - 1, 0)],
                Mq.x, Mq.y, Mq.z, Mq.w,
                rp2[min(gx + 4, W - 1)], rp2[min(gx + 5, W - 1)]};
            #pragma unroll
            for (int dc = -2; dc <= 2; ++dc) {
                if (dr == 0 && dc == 0) continue;
                const float b = ra + (float)(dc * dc) * nay;
                if (b < TH2) continue;
                #pragma unroll
                for (int j = 0; j < 4; ++j) {
                    const float nb = w8[2 + j + dc];
                    const float d  = nb - cen[j];
                    const float tt = fmaf(d * d, ncr, b);
                    const float w  = EXP2(tt);
                    num[j] = fmaf(w, nb, num[j]);
                    den[j] += w;
                }
            }
        }
        float4 o;
        o.x = num[0] * RCP(den[0]);
        o.y = num[1] * RCP(den[1]);
        o.z = num[2] * RCP(den[2]);
        o.w = num[3] * RCP(den[3]);
        *(float4*)op = o;
    }
}

#define DTX 64            // tile 64 x 16 px, 256 threads x 4 px
#define DTY 16

// =======================================================================
// Primary: single cooperative launch, 3 passes, grid.sync between.
// =======================================================================

__global__ __launch_bounds__(256)
void bilat3_coop(const float* __restrict__ x, float* __restrict__ out,
                 float* __restrict__ ws,
                 const float* __restrict__ sxyz, const float* __restrict__ srr,
                 int H, int W, int BC)
{
    cg::grid_group grid = cg::this_grid();

    const int tid = threadIdx.x;
    const int q = tid & 15;           // quad 0..15
    const int r = tid >> 4;           // row  0..15
    const int tpx = W / DTX, tpy = H / DTY;
    const int tilesPerImg = tpx * tpy;
    const int ntiles = tilesPerImg * BC;
    const float L2E = 1.4426950408889634f;

    const float* src = x;
    float* dst = out;

    #pragma unroll 1
    for (int p = 0; p < 3; ++p) {
        const float sx = sxyz[2 * p], sy = sxyz[2 * p + 1], sr = srr[p];
        const float ncr = -0.5f / (sr * sr) * L2E;
        const float nax = -0.5f / (sx * sx) * L2E;
        const float nay = -0.5f / (sy * sy) * L2E;
        const bool prune = (4.f * nax < TH2) && (4.f * nay < TH2);
        const v2f ncr2 = {ncr, ncr};

        for (int t = blockIdx.x; t < ntiles; t += gridDim.x) {
            const int z   = t / tilesPerImg;
            const int rem = t - z * tilesPerImg;
            const int by  = rem / tpx;
            const int bx  = rem - by * tpx;
            const int gx  = bx * DTX + 4 * q;
            const int gy  = by * DTY + r;
            const size_t off = (size_t)z * (size_t)H * (size_t)W;
            bilat_px4(src + off, dst + off, gx, gy, H, W,
                      ncr, nax, nay, prune, ncr2);
        }

        if (p < 2) {
            __threadfence();          // device-scope release (cross-XCD)
            grid.sync();              // acquire handled by the sync atomics
        }
        // pointer schedule: x->out, out->ws, ws->out (no dynamic indexing)
        if (p == 0) { src = out; dst = ws; }
        else        { src = ws;  dst = out; }
    }
}

// =======================================================================
// Fallback 1: three plain launches (round-12 path, proven).
// =======================================================================

__global__ __launch_bounds__(256)
void bilat_direct(const float* __restrict__ in, float* __restrict__ out,
                  const float* __restrict__ sxyz, const float* __restrict__ srr,
                  int p, int H, int W)
{
    const int tid = threadIdx.x;
    const int q = tid & 15;
    const int r = tid >> 4;
    const int gx = blockIdx.x * DTX + 4 * q;
    const int gy = blockIdx.y * DTY + r;
    const size_t img_off = (size_t)blockIdx.z * (size_t)H * (size_t)W;

    const float L2E = 1.4426950408889634f;
    const float sx = sxyz[2 * p], sy = sxyz[2 * p + 1], sr = srr[p];
    const float ncr = -0.5f / (sr * sr) * L2E;
    const float nax = -0.5f / (sx * sx) * L2E;
    const float nay = -0.5f / (sy * sy) * L2E;
    const bool prune = (4.f * nax < TH2) && (4.f * nay < TH2);
    const v2f ncr2 = {ncr, ncr};

    bilat_px4(in + img_off, out + img_off, gx, gy, H, W,
              ncr, nax, nay, prune, ncr2);
}

// =======================================================================
// Fallback 2: fused 3-pass LDS kernel (rounds 9-11) if ws too small.
// =======================================================================

#define TILE_X 64
#define TILE_Y 32
#define S0R 44
#define S0C 92
#define S1R 40
#define S1C 84
#define S2R 36
#define S2C 76

__device__ __forceinline__ void mkrow6(const float* p, float* w6)
{
    const float4 L = *(const float4*)(p - 4);
    const float4 M = *(const float4*)(p);
    const float4 R = *(const float4*)(p + 4);
    w6[0] = L.w; w6[1] = M.x; w6[2] = M.y; w6[3] = M.z; w6[4] = M.w;
    w6[5] = R.x;
}

template<int NR, int NC>
__device__ __forceinline__ void replicate_fill(float* buf, int rlo, int rhi,
                                               int vlo, int vhi, int tid)
{
    if (rlo == 0 && vlo == 0 && rhi == NR - 1 && vhi == NC - 1) return;
    for (int t = tid; t < NR * NC; t += 256) {
        const int r = t / NC, v = t - r * NC;
        const int rs = min(max(r, rlo), rhi);
        const int vs = min(max(v, vlo), vhi);
        if (rs != r || vs != v) buf[r * NC + v] = buf[rs * NC + vs];
    }
}

template<int NQ, int NRH, int SST, int DSTST, bool TOG>
__device__ __forceinline__ void bilat_tile_pass(
    const float* __restrict__ src, float* __restrict__ dst,
    float* __restrict__ gout, int W,
    int tid, float ncr, float nax, float nay, bool prune)
{
    const v2f ncr2 = {ncr, ncr};
    for (int t = tid; t < NQ * NRH; t += 256) {
        const int rp = t / NQ;
        const int q  = t - rp * NQ;
        const int r0 = 2 * rp;
        const float* cp = src + (r0 + 2) * SST + 4 * q + 4;

        if (prune) {
            float w0[6], w1[6], w2[6], w3[6];
            mkrow6(cp - SST,     w0);
            mkrow6(cp,           w1);
            mkrow6(cp + SST,     w2);
            mkrow6(cp + 2 * SST, w3);
            const float4 oA = core3x3(w0, w1, w2, nax, nay, ncr2);
            const float4 oB = core3x3(w1, w2, w3, nax, nay, ncr2);
            if (TOG) {
                *(float4*)(gout + (r0    ) * W + 4 * q) = oA;
                *(float4*)(gout + (r0 + 1) * W + 4 * q) = oB;
            } else {
                *(float4*)(dst + (r0    ) * DSTST + 4 * q) = oA;
                *(float4*)(dst + (r0 + 1) * DSTST + 4 * q) = oB;
            }
        } else {
            #pragma unroll
            for (int rr = 0; rr < 2; ++rr) {
                const float* cp2 = cp + rr * SST;
                const float4 M0 = *(const float4*)cp2;
                float cen[4] = {M0.x, M0.y, M0.z, M0.w};
                float num[4] = {M0.x, M0.y, M0.z, M0.w};
                float den[4] = {1.f, 1.f, 1.f, 1.f};
                #pragma unroll
                for (int dr = -2; dr <= 2; ++dr) {
                    const float ra = (float)(dr * dr) * nax;
                    const float rbest = dr ? ra : nay;
                    if (rbest < TH2) continue;
                    const float* rp2 = cp2 + dr * SST;
                    const float4 Lq = *(const float4*)(rp2 - 4);
                    const float4 Mq = *(const float4*)(rp2);
                    const float4 Rq = *(const float4*)(rp2 + 4);
                    const float w8[8] = {Lq.z, Lq.w, Mq.x, Mq.y, Mq.z, Mq.w,
                                         Rq.x, Rq.y};
                    #pragma unroll
                    for (int dc = -2; dc <= 2; ++dc) {
                        if (dr == 0 && dc == 0) continue;
                        const float b = ra + (float)(dc * dc) * nay;
                        if (b < TH2) continue;
                        #pragma unroll
                        for (int j = 0; j < 4; ++j) {
                            const float nb = w8[2 + j + dc];
                            const float d  = nb - cen[j];
                            const float tt = fmaf(d * d, ncr, b);
                            const float w  = EXP2(tt);
                            num[j] = fmaf(w, nb, num[j]);
                            den[j] += w;
                        }
                    }
                }
                float4 o;
                o.x = num[0] * RCP(den[0]);
                o.y = num[1] * RCP(den[1]);
                o.z = num[2] * RCP(den[2]);
                o.w = num[3] * RCP(den[3]);
                if (TOG) *(float4*)(gout + (r0 + rr) * W + 4 * q) = o;
                else     *(float4*)(dst + (r0 + rr) * DSTST + 4 * q) = o;
            }
        }
    }
}

template<int NR, int NC, int RO, int CO>
__device__ __forceinline__ void stage_aperture(const float* __restrict__ img,
                                               float* __restrict__ buf,
                                               int Y0, int X0, int H, int W,
                                               int tid)
{
    const int NQ = NC / 4;
    for (int t = tid; t < NR * NQ; t += 256) {
        const int r = t / NQ, k = t - r * NQ;
        const int gy = Y0 + RO + r;
        const int gx = X0 + CO + 4 * k;
        float4 v;
        if (gy >= 0 && gy < H && gx >= 0 && gx + 3 < W) {
            v = *(const float4*)(img + (size_t)gy * W + gx);
        } else {
            const size_t rb = (size_t)min(max(gy, 0), H - 1) * W;
            v.x = img[rb + min(max(gx    , 0), W - 1)];
            v.y = img[rb + min(max(gx + 1, 0), W - 1)];
            v.z = img[rb + min(max(gx + 2, 0), W - 1)];
            v.w = img[rb + min(max(gx + 3, 0), W - 1)];
        }
        *(float4*)(buf + r * NC + 4 * k) = v;
    }
}

__global__ __launch_bounds__(256)
void bilat3_fused(const float* __restrict__ in, float* __restrict__ out,
                  const float* __restrict__ sxyz, const float* __restrict__ srr,
                  int H, int W)
{
    __shared__ __align__(16) float buf0[S0R * S0C];
    __shared__ __align__(16) float buf1[S1R * S1C];

    const int tid = threadIdx.x;
    const int X0 = blockIdx.x * TILE_X;
    const int Y0 = blockIdx.y * TILE_Y;
    const size_t img_off = (size_t)blockIdx.z * (size_t)H * (size_t)W;

    const float L2E = 1.4426950408889634f;
    float ncr[3], nax[3], nay[3];
    bool prune[3];
    #pragma unroll
    for (int p = 0; p < 3; ++p) {
        const float sx = sxyz[2 * p], sy = sxyz[2 * p + 1], sr = srr[p];
        ncr[p] = -0.5f / (sr * sr) * L2E;
        nax[p] = -0.5f / (sx * sx) * L2E;
        nay[p] = -0.5f / (sy * sy) * L2E;
        prune[p] = (4.f * nax[p] < TH2) && (4.f * nay[p] < TH2);
    }

    stage_aperture<S0R, S0C, -6, -12>(in + img_off, buf0, Y0, X0, H, W, tid);
    __syncthreads();

    bilat_tile_pass<S1C / 4, S1R / 2, S0C, S1C, false>(
        buf0, buf1, nullptr, W, tid, ncr[0], nax[0], nay[0], prune[0]);
    __syncthreads();
    replicate_fill<S1R, S1C>(buf1,
        max(0, 4 - Y0), min(S1R - 1, (H - 1) - (Y0 - 4)),
        max(0, 8 - X0), min(S1C - 1, (W - 1) - (X0 - 8)), tid);
    __syncthreads();

    float* buf2 = buf0;
    bilat_tile_pass<S2C / 4, S2R / 2, S1C, S2C, false>(
        buf1, buf2, nullptr, W, tid, ncr[1], nax[1], nay[1], prune[1]);
    __syncthreads();
    replicate_fill<S2R, S2C>(buf2,
        max(0, 2 - Y0), min(S2R - 1, (H - 1) - (Y0 - 2)),
        max(0, 4 - X0), min(S2C - 1, (W - 1) - (X0 - 4)), tid);
    __syncthreads();

    float* gout = out + img_off + (size_t)Y0 * W + X0;
    bilat_tile_pass<TILE_X / 4, TILE_Y / 2, S2C, 0, true>(
        buf2, nullptr, gout, W, tid, ncr[2], nax[2], nay[2], prune[2]);
}

// =======================================================================

extern "C" void kernel_launch(void* const* d_in, const int* in_sizes, int n_in,
                              void* d_out, int out_size, void* d_ws, size_t ws_size,
                              hipStream_t stream)
{
    const float* x    = (const float*)d_in[0];
    const float* sxyz = (const float*)d_in[1];   // [3,2]
    const float* sr   = (const float*)d_in[2];   // [3]
    float* out = (float*)d_out;

    const int H = 512, W = 512;
    const int BC = in_sizes[0] / (H * W);        // 32
    const int ntiles = (W / DTX) * (H / DTY) * BC;   // 8192

    const size_t img_bytes = (size_t)BC * H * W * sizeof(float);
    const bool have_ws = d_ws && ws_size >= img_bytes;

    // Co-residency capacity for the cooperative kernel (cached; host-side
    // queries only -- graph-capture-safe, no alloc/sync).
    static int coopGrid = -2;
    if (coopGrid == -2) {
        coopGrid = 0;
        int dev = 0;
        hipDeviceProp_t prop;
        if (hipGetDevice(&dev) == hipSuccess &&
            hipGetDeviceProperties(&prop, dev) == hipSuccess &&
            prop.cooperativeLaunch) {
            int maxB = 0;
            if (hipOccupancyMaxActiveBlocksPerMultiprocessor(
                    &maxB, bilat3_coop, 256, 0) == hipSuccess && maxB > 0) {
                coopGrid = maxB * prop.multiProcessorCount;
            }
        }
    }

    bool done = false;
    if (have_ws && coopGrid > 0) {
        float* ws = (float*)d_ws;
        int nblk = coopGrid < ntiles ? coopGrid : ntiles;
        int Ha = H, Wa = W, BCa = BC;
        void* args[] = {(void*)&x, (void*)&out, (void*)&ws,
                        (void*)&sxyz, (void*)&sr,
                        (void*)&Ha, (void*)&Wa, (void*)&BCa};
        if (hipLaunchCooperativeKernel(bilat3_coop, dim3(nblk), dim3(256),
                                       args, 0, stream) == hipSuccess) {
            done = true;
        }
    }

    if (!done && have_ws) {
        float* ws = (float*)d_ws;
        dim3 block(256);
        dim3 grid(W / DTX, H / DTY, BC);         // 8 x 32 x 32 = 8192 blocks
        bilat_direct<<<grid, block, 0, stream>>>(x,   out, sxyz, sr, 0, H, W);
        bilat_direct<<<grid, block, 0, stream>>>(out, ws,  sxyz, sr, 1, H, W);
        bilat_direct<<<grid, block, 0, stream>>>(ws,  out, sxyz, sr, 2, H, W);
        done = true;
    }

    if (!done) {
        dim3 block(256);
        dim3 grid(W / TILE_X, H / TILE_Y, BC);   // 8 x 16 x 32 = 4096 blocks
        bilat3_fused<<<grid, block, 0, stream>>>(x, out, sxyz, sr, H, W);
    }
}

// Round 7
// 133.486 us; speedup vs baseline: 3.4976x; 3.4976x over previous
//
#include <hip/hip_runtime.h>

// Bilateral 5x5, 3 chained passes. [32,1,512,512] fp32, replicate padding,
// w = exp2(dr^2*nax + dc^2*nay + d^2*ncr).
//
// Round-15 = round-14 with the compile fix: __builtin_nontemporal_store
// requires a clang ext-vector pointer, not HIP's float4 class -> store
// through v4f (identical 16B layout).
//
// Round-14 rationale: coop reverted (860us, grid.sync spins on HBM atomics
// across 8 non-coherent XCDs). Proven 3-launch direct-global path (129.8us)
// with two per-pass cuts:
//   (a) 2-row units: 8 px/thread, 4 shared window rows -> 12 VMEM loads
//       per 8 px (was 18), half the addressing + stores per px.
//   (b) nontemporal stores: round-13 counters proved inter-pass reads come
//       from HBM (FETCH = 3x image even inside one kernel), so L2
//       allocation of 33MB/pass of output is pure thrash; nt evicts first.
// Passes are latency-bound (VALUBusy ~53%, HBM ~15%; neither saturated),
// so fewer memory instructions per px is the remaining lever.
//
// Pruning (round 3): taps with spatial log2-weight < TH2 skipped via
// block-uniform branches -> effective 3x3 for sigma=0.5 (8 exps/px).
// Generic 5x5 path kept for large sigma (cold).

typedef float v2f __attribute__((ext_vector_type(2)));
typedef float v4f __attribute__((ext_vector_type(4)));

#define EXP2(x) __builtin_amdgcn_exp2f(x)
#define RCP(x)  __builtin_amdgcn_rcpf(x)
#define TH2 (-10.0f)

// ---------------- shared tap core (validated rounds 8-13) ----------------

// One packed tap-pair: 5 pk ops + 2 exp for 2 pixels.
__device__ __forceinline__ void tap_pair(v2f nb, v2f ce, v2f& nu, v2f& de,
                                         float b, v2f ncr2)
{
    v2f d  = nb - ce;                                   // pk_add
    v2f tt = __builtin_elementwise_fma(d * d, ncr2,
                                       (v2f){b, b});    // pk_mul+pk_fma
    v2f w  = {EXP2(tt.x), EXP2(tt.y)};
    nu = __builtin_elementwise_fma(w, nb, nu);          // pk_fma
    de += w;                                            // pk_add
}

// All horizontal taps of one window row against centers c01/c23.
__device__ __forceinline__ void row_taps(const float* w6, v2f c01, v2f c23,
                                         v2f& n01, v2f& n23, v2f& d01, v2f& d23,
                                         float bm, float b0, float bp,
                                         bool skip0, v2f ncr2)
{
    tap_pair((v2f){w6[0], w6[1]}, c01, n01, d01, bm, ncr2);   // dc=-1
    tap_pair((v2f){w6[2], w6[3]}, c23, n23, d23, bm, ncr2);
    if (!skip0) {
        tap_pair((v2f){w6[1], w6[2]}, c01, n01, d01, b0, ncr2); // dc=0
        tap_pair((v2f){w6[3], w6[4]}, c23, n23, d23, b0, ncr2);
    }
    tap_pair((v2f){w6[2], w6[3]}, c01, n01, d01, bp, ncr2);   // dc=+1
    tap_pair((v2f){w6[4], w6[5]}, c23, n23, d23, bp, ncr2);
}

// Packed 3x3 bilateral core for 4 px: 16 tap-pairs = 80 pk ops + 32 exp.
__device__ __forceinline__ v4f core3x3(const float* wm, const float* wc,
                                       const float* wp,
                                       float nax, float nay, v2f ncr2)
{
    v2f c01 = {wc[1], wc[2]}, c23 = {wc[3], wc[4]};
    v2f n01 = c01, n23 = c23;               // center tap, w == 1
    v2f d01 = {1.f, 1.f}, d23 = {1.f, 1.f};
    const float bd = nax + nay;
    row_taps(wc, c01, c23, n01, n23, d01, d23, nay, 0.0f, nay, true,  ncr2);
    row_taps(wm, c01, c23, n01, n23, d01, d23, bd,  nax,  bd,  false, ncr2);
    row_taps(wp, c01, c23, n01, n23, d01, d23, bd,  nax,  bd,  false, ncr2);
    v4f o;
    o.x = n01.x * RCP(d01.x);
    o.y = n01.y * RCP(d01.y);
    o.z = n23.x * RCP(d23.x);
    o.w = n23.y * RCP(d23.y);
    return o;
}

// 6-wide window row: aligned quad [gx..gx+3] + clamped scalars gx-1, gx+4.
__device__ __forceinline__ void ld6(const float* __restrict__ rowp, int gx,
                                    int W, float* w6)
{
    const float4 M = *(const float4*)(rowp + gx);       // 16B aligned
    const float  lw = rowp[max(gx - 1, 0)];             // branchless clamp
    const float  rx = rowp[min(gx + 4, W - 1)];
    w6[0] = lw;  w6[1] = M.x; w6[2] = M.y; w6[3] = M.z; w6[4] = M.w;
    w6[5] = rx;
}

// =======================================================================
// Primary: direct-global pass, 2-row (8-px) units, nontemporal stores.
// =======================================================================

#define DTX 64            // tile 64 x 32 px: 16 quads x 16 row-pairs
#define DTY 32

__global__ __launch_bounds__(256)
void bilat_direct2(const float* __restrict__ in, float* __restrict__ out,
                   const float* __restrict__ sxyz, const float* __restrict__ srr,
                   int p, int H, int W)
{
    const int tid = threadIdx.x;
    const int q  = tid & 15;          // quad 0..15
    const int rp = tid >> 4;          // row-pair 0..15
    const int gx = blockIdx.x * DTX + 4 * q;
    const int gy = blockIdx.y * DTY + 2 * rp;      // rows gy, gy+1
    const size_t img_off = (size_t)blockIdx.z * (size_t)H * (size_t)W;
    const float* __restrict__ img = in + img_off;

    const float L2E = 1.4426950408889634f;
    const float sx = sxyz[2 * p], sy = sxyz[2 * p + 1], sr = srr[p];
    const float ncr = -0.5f / (sr * sr) * L2E;
    const float nax = -0.5f / (sx * sx) * L2E;
    const float nay = -0.5f / (sy * sy) * L2E;
    const bool prune = (4.f * nax < TH2) && (4.f * nay < TH2);
    const v2f ncr2 = {ncr, ncr};

    float* opA = out + img_off + (size_t)gy * W + gx;
    float* opB = opA + W;

    if (prune) {
        // 4 window rows shared by the two 3x3 cores: gy-1, gy, gy+1, gy+2
        const float* r0 = img + (size_t)max(gy - 1, 0)     * W;
        const float* r1 = img + (size_t)gy                 * W;
        const float* r2 = img + (size_t)(gy + 1)           * W;  // gy+1 < H
        const float* r3 = img + (size_t)min(gy + 2, H - 1) * W;
        float w0[6], w1[6], w2[6], w3[6];
        ld6(r0, gx, W, w0);               // 12 VMEM loads total for 8 px
        ld6(r1, gx, W, w1);
        ld6(r2, gx, W, w2);
        ld6(r3, gx, W, w3);
        const v4f oA = core3x3(w0, w1, w2, nax, nay, ncr2);
        const v4f oB = core3x3(w1, w2, w3, nax, nay, ncr2);
        __builtin_nontemporal_store(oA, (v4f*)opA);
        __builtin_nontemporal_store(oB, (v4f*)opB);
    } else {
        // ---- generic 5x5, streaming per row (cold path) ----
        #pragma unroll
        for (int rr = 0; rr < 2; ++rr) {
            const int cy = gy + rr;
            const float4 C = *(const float4*)(img + (size_t)cy * W + gx);
            float cen[4] = {C.x, C.y, C.z, C.w};
            float num[4] = {C.x, C.y, C.z, C.w};
            float den[4] = {1.f, 1.f, 1.f, 1.f};
            #pragma unroll
            for (int dr = -2; dr <= 2; ++dr) {
                const float ra = (float)(dr * dr) * nax;
                const float rbest = dr ? ra : nay;
                if (rbest < TH2) continue;
                const float* rw = img + (size_t)min(max(cy + dr, 0), H - 1) * W;
                const float4 Mq = *(const float4*)(rw + gx);
                const float w8[8] = {
                    rw[max(gx - 2, 0)], rw[max(gx - 1, 0)],
                    Mq.x, Mq.y, Mq.z, Mq.w,
                    rw[min(gx + 4, W - 1)], rw[min(gx + 5, W - 1)]};
                #pragma unroll
                for (int dc = -2; dc <= 2; ++dc) {
                    if (dr == 0 && dc == 0) continue;
                    const float b = ra + (float)(dc * dc) * nay;
                    if (b < TH2) continue;
                    #pragma unroll
                    for (int j = 0; j < 4; ++j) {
                        const float nb = w8[2 + j + dc];
                        const float d  = nb - cen[j];
                        const float tt = fmaf(d * d, ncr, b);
                        const float w  = EXP2(tt);
                        num[j] = fmaf(w, nb, num[j]);
                        den[j] += w;
                    }
                }
            }
            v4f o;
            o.x = num[0] * RCP(den[0]);
            o.y = num[1] * RCP(den[1]);
            o.z = num[2] * RCP(den[2]);
            o.w = num[3] * RCP(den[3]);
            __builtin_nontemporal_store(o, (v4f*)(rr ? opB : opA));
        }
    }
}

// =======================================================================
// Fallback: fused 3-pass LDS kernel (rounds 9-11) if ws too small.
// =======================================================================

#define TILE_X 64
#define TILE_Y 32
#define S0R 44
#define S0C 92
#define S1R 40
#define S1C 84
#define S2R 36
#define S2C 76

__device__ __forceinline__ void mkrow6(const float* p, float* w6)
{
    const float4 L = *(const float4*)(p - 4);
    const float4 M = *(const float4*)(p);
    const float4 R = *(const float4*)(p + 4);
    w6[0] = L.w; w6[1] = M.x; w6[2] = M.y; w6[3] = M.z; w6[4] = M.w;
    w6[5] = R.x;
}

template<int NR, int NC>
__device__ __forceinline__ void replicate_fill(float* buf, int rlo, int rhi,
                                               int vlo, int vhi, int tid)
{
    if (rlo == 0 && vlo == 0 && rhi == NR - 1 && vhi == NC - 1) return;
    for (int t = tid; t < NR * NC; t += 256) {
        const int r = t / NC, v = t - r * NC;
        const int rs = min(max(r, rlo), rhi);
        const int vs = min(max(v, vlo), vhi);
        if (rs != r || vs != v) buf[r * NC + v] = buf[rs * NC + vs];
    }
}

template<int NQ, int NRH, int SST, int DSTST, bool TOG>
__device__ __forceinline__ void bilat_tile_pass(
    const float* __restrict__ src, float* __restrict__ dst,
    float* __restrict__ gout, int W,
    int tid, float ncr, float nax, float nay, bool prune)
{
    const v2f ncr2 = {ncr, ncr};
    for (int t = tid; t < NQ * NRH; t += 256) {
        const int rp = t / NQ;
        const int q  = t - rp * NQ;
        const int r0 = 2 * rp;
        const float* cp = src + (r0 + 2) * SST + 4 * q + 4;

        if (prune) {
            float w0[6], w1[6], w2[6], w3[6];
            mkrow6(cp - SST,     w0);
            mkrow6(cp,           w1);
            mkrow6(cp + SST,     w2);
            mkrow6(cp + 2 * SST, w3);
            const v4f oA = core3x3(w0, w1, w2, nax, nay, ncr2);
            const v4f oB = core3x3(w1, w2, w3, nax, nay, ncr2);
            if (TOG) {
                *(v4f*)(gout + (r0    ) * W + 4 * q) = oA;
                *(v4f*)(gout + (r0 + 1) * W + 4 * q) = oB;
            } else {
                *(v4f*)(dst + (r0    ) * DSTST + 4 * q) = oA;
                *(v4f*)(dst + (r0 + 1) * DSTST + 4 * q) = oB;
            }
        } else {
            #pragma unroll
            for (int rr = 0; rr < 2; ++rr) {
                const float* cp2 = cp + rr * SST;
                const float4 M0 = *(const float4*)cp2;
                float cen[4] = {M0.x, M0.y, M0.z, M0.w};
                float num[4] = {M0.x, M0.y, M0.z, M0.w};
                float den[4] = {1.f, 1.f, 1.f, 1.f};
                #pragma unroll
                for (int dr = -2; dr <= 2; ++dr) {
                    const float ra = (float)(dr * dr) * nax;
                    const float rbest = dr ? ra : nay;
                    if (rbest < TH2) continue;
                    const float* rp2 = cp2 + dr * SST;
                    const float4 Lq = *(const float4*)(rp2 - 4);
                    const float4 Mq = *(const float4*)(rp2);
                    const float4 Rq = *(const float4*)(rp2 + 4);
                    const float w8[8] = {Lq.z, Lq.w, Mq.x, Mq.y, Mq.z, Mq.w,
                                         Rq.x, Rq.y};
                    #pragma unroll
                    for (int dc = -2; dc <= 2; ++dc) {
                        if (dr == 0 && dc == 0) continue;
                        const float b = ra + (float)(dc * dc) * nay;
                        if (b < TH2) continue;
                        #pragma unroll
                        for (int j = 0; j < 4; ++j) {
                            const float nb = w8[2 + j + dc];
                            const float d  = nb - cen[j];
                            const float tt = fmaf(d * d, ncr, b);
                            const float w  = EXP2(tt);
                            num[j] = fmaf(w, nb, num[j]);
                            den[j] += w;
                        }
                    }
                }
                v4f o;
                o.x = num[0] * RCP(den[0]);
                o.y = num[1] * RCP(den[1]);
                o.z = num[2] * RCP(den[2]);
                o.w = num[3] * RCP(den[3]);
                if (TOG) *(v4f*)(gout + (r0 + rr) * W + 4 * q) = o;
                else     *(v4f*)(dst + (r0 + rr) * DSTST + 4 * q) = o;
            }
        }
    }
}

template<int NR, int NC, int RO, int CO>
__device__ __forceinline__ void stage_aperture(const float* __restrict__ img,
                                               float* __restrict__ buf,
                                               int Y0, int X0, int H, int W,
                                               int tid)
{
    const int NQ = NC / 4;
    for (int t = tid; t < NR * NQ; t += 256) {
        const int r = t / NQ, k = t - r * NQ;
        const int gy = Y0 + RO + r;
        const int gx = X0 + CO + 4 * k;
        float4 v;
        if (gy >= 0 && gy < H && gx >= 0 && gx + 3 < W) {
            v = *(const float4*)(img + (size_t)gy * W + gx);
        } else {
            const size_t rb = (size_t)min(max(gy, 0), H - 1) * W;
            v.x = img[rb + min(max(gx    , 0), W - 1)];
            v.y = img[rb + min(max(gx + 1, 0), W - 1)];
            v.z = img[rb + min(max(gx + 2, 0), W - 1)];
            v.w = img[rb + min(max(gx + 3, 0), W - 1)];
        }
        *(float4*)(buf + r * NC + 4 * k) = v;
    }
}

__global__ __launch_bounds__(256)
void bilat3_fused(const float* __restrict__ in, float* __restrict__ out,
                  const float* __restrict__ sxyz, const float* __restrict__ srr,
                  int H, int W)
{
    __shared__ __align__(16) float buf0[S0R * S0C];
    __shared__ __align__(16) float buf1[S1R * S1C];

    const int tid = threadIdx.x;
    const int X0 = blockIdx.x * TILE_X;
    const int Y0 = blockIdx.y * TILE_Y;
    const size_t img_off = (size_t)blockIdx.z * (size_t)H * (size_t)W;

    const float L2E = 1.4426950408889634f;
    float ncr[3], nax[3], nay[3];
    bool prune[3];
    #pragma unroll
    for (int p = 0; p < 3; ++p) {
        const float sx = sxyz[2 * p], sy = sxyz[2 * p + 1], sr = srr[p];
        ncr[p] = -0.5f / (sr * sr) * L2E;
        nax[p] = -0.5f / (sx * sx) * L2E;
        nay[p] = -0.5f / (sy * sy) * L2E;
        prune[p] = (4.f * nax[p] < TH2) && (4.f * nay[p] < TH2);
    }

    stage_aperture<S0R, S0C, -6, -12>(in + img_off, buf0, Y0, X0, H, W, tid);
    __syncthreads();

    bilat_tile_pass<S1C / 4, S1R / 2, S0C, S1C, false>(
        buf0, buf1, nullptr, W, tid, ncr[0], nax[0], nay[0], prune[0]);
    __syncthreads();
    replicate_fill<S1R, S1C>(buf1,
        max(0, 4 - Y0), min(S1R - 1, (H - 1) - (Y0 - 4)),
        max(0, 8 - X0), min(S1C - 1, (W - 1) - (X0 - 8)), tid);
    __syncthreads();

    float* buf2 = buf0;
    bilat_tile_pass<S2C / 4, S2R / 2, S1C, S2C, false>(
        buf1, buf2, nullptr, W, tid, ncr[1], nax[1], nay[1], prune[1]);
    __syncthreads();
    replicate_fill<S2R, S2C>(buf2,
        max(0, 2 - Y0), min(S2R - 1, (H - 1) - (Y0 - 2)),
        max(0, 4 - X0), min(S2C - 1, (W - 1) - (X0 - 4)), tid);
    __syncthreads();

    float* gout = out + img_off + (size_t)Y0 * W + X0;
    bilat_tile_pass<TILE_X / 4, TILE_Y / 2, S2C, 0, true>(
        buf2, nullptr, gout, W, tid, ncr[2], nax[2], nay[2], prune[2]);
}

// =======================================================================

extern "C" void kernel_launch(void* const* d_in, const int* in_sizes, int n_in,
                              void* d_out, int out_size, void* d_ws, size_t ws_size,
                              hipStream_t stream)
{
    const float* x    = (const float*)d_in[0];
    const float* sxyz = (const float*)d_in[1];   // [3,2]
    const float* sr   = (const float*)d_in[2];   // [3]
    float* out = (float*)d_out;

    const int H = 512, W = 512;
    const int BC = in_sizes[0] / (H * W);        // 32

    const size_t img_bytes = (size_t)BC * H * W * sizeof(float);
    if (d_ws && ws_size >= img_bytes) {
        float* ws = (float*)d_ws;
        dim3 block(256);
        dim3 grid(W / DTX, H / DTY, BC);         // 8 x 16 x 32 = 4096 blocks
        // pass 1: in -> out, pass 2: out -> ws, pass 3: ws -> out
        bilat_direct2<<<grid, block, 0, stream>>>(x,   out, sxyz, sr, 0, H, W);
        bilat_direct2<<<grid, block, 0, stream>>>(out, ws,  sxyz, sr, 1, H, W);
        bilat_direct2<<<grid, block, 0, stream>>>(ws,  out, sxyz, sr, 2, H, W);
    } else {
        dim3 block(256);
        dim3 grid(W / TILE_X, H / TILE_Y, BC);   // 8 x 16 x 32 = 4096 blocks
        bilat3_fused<<<grid, block, 0, stream>>>(x, out, sxyz, sr, H, W);
    }
}

// Round 8
// 129.180 us; speedup vs baseline: 3.6142x; 1.0333x over previous
//
#include <hip/hip_runtime.h>

// Bilateral 5x5, 3 chained passes. [32,1,512,512] fp32, replicate padding,
// w = exp2(dr^2*nax + dc^2*nay + d^2*ncr).
//
// Round-16: EXACT REVERT to round-12 (129.8us, session best). Round-15's
// 2-row units + nontemporal stores regressed to 133.5us: halving the
// thread count (4096x8px vs 8192x4px) cost more in lost TLP (latency
// hiding) than the 33% VMEM-op cut saved. Confirmed levers, all explored:
//   - fusion (3.98x / 2.34x overscan): loses, compute is the scarce pipe
//   - cooperative single launch: catastrophic (grid.sync via HBM atomics)
//   - LDS staging + barrier: loses to direct-global (latency-bound)
//   - per-unit op-count cuts (2-row, fewer LDS reads): neutral/regress
// Structure: 3 launches, each pass direct global->global, 4px/thread,
// 8192 blocks, no LDS, no barrier. Budget: ~42us harness ws-poison fill +
// ~20us harness fixed + ~67us GPU (3 passes + 2 in-order launch gaps).
//
// Pruning (round 3): taps with spatial log2-weight < TH2 skipped via
// block-uniform branches -> effective 3x3 for sigma=0.5 (8 exps/px).
// Generic 5x5 path kept for large sigma (cold).

typedef float v2f __attribute__((ext_vector_type(2)));

#define EXP2(x) __builtin_amdgcn_exp2f(x)
#define RCP(x)  __builtin_amdgcn_rcpf(x)
#define TH2 (-10.0f)

// ---------------- shared tap core (validated rounds 8-15) ----------------

// One packed tap-pair: 5 pk ops + 2 exp for 2 pixels.
__device__ __forceinline__ void tap_pair(v2f nb, v2f ce, v2f& nu, v2f& de,
                                         float b, v2f ncr2)
{
    v2f d  = nb - ce;                                   // pk_add
    v2f tt = __builtin_elementwise_fma(d * d, ncr2,
                                       (v2f){b, b});    // pk_mul+pk_fma
    v2f w  = {EXP2(tt.x), EXP2(tt.y)};
    nu = __builtin_elementwise_fma(w, nb, nu);          // pk_fma
    de += w;                                            // pk_add
}

// All horizontal taps of one window row against centers c01/c23.
__device__ __forceinline__ void row_taps(const float* w6, v2f c01, v2f c23,
                                         v2f& n01, v2f& n23, v2f& d01, v2f& d23,
                                         float bm, float b0, float bp,
                                         bool skip0, v2f ncr2)
{
    tap_pair((v2f){w6[0], w6[1]}, c01, n01, d01, bm, ncr2);   // dc=-1
    tap_pair((v2f){w6[2], w6[3]}, c23, n23, d23, bm, ncr2);
    if (!skip0) {
        tap_pair((v2f){w6[1], w6[2]}, c01, n01, d01, b0, ncr2); // dc=0
        tap_pair((v2f){w6[3], w6[4]}, c23, n23, d23, b0, ncr2);
    }
    tap_pair((v2f){w6[2], w6[3]}, c01, n01, d01, bp, ncr2);   // dc=+1
    tap_pair((v2f){w6[4], w6[5]}, c23, n23, d23, bp, ncr2);
}

// Packed 3x3 bilateral core for 4 px: 16 tap-pairs = 80 pk ops + 32 exp.
__device__ __forceinline__ float4 core3x3(const float* wm, const float* wc,
                                          const float* wp,
                                          float nax, float nay, v2f ncr2)
{
    v2f c01 = {wc[1], wc[2]}, c23 = {wc[3], wc[4]};
    v2f n01 = c01, n23 = c23;               // center tap, w == 1
    v2f d01 = {1.f, 1.f}, d23 = {1.f, 1.f};
    const float bd = nax + nay;
    row_taps(wc, c01, c23, n01, n23, d01, d23, nay, 0.0f, nay, true,  ncr2);
    row_taps(wm, c01, c23, n01, n23, d01, d23, bd,  nax,  bd,  false, ncr2);
    row_taps(wp, c01, c23, n01, n23, d01, d23, bd,  nax,  bd,  false, ncr2);
    float4 o;
    o.x = n01.x * RCP(d01.x);
    o.y = n01.y * RCP(d01.y);
    o.z = n23.x * RCP(d23.x);
    o.w = n23.y * RCP(d23.y);
    return o;
}

// =======================================================================
// Primary path: direct-global pass, no LDS, no barrier (round-12).
// =======================================================================

#define DTX 64            // tile 64 x 16 px, 256 threads x 4 px
#define DTY 16

// 6-wide window row: aligned quad [gx..gx+3] + clamped scalars gx-1, gx+4.
__device__ __forceinline__ void ld6(const float* __restrict__ rowp, int gx,
                                    int W, float* w6)
{
    const float4 M = *(const float4*)(rowp + gx);       // 16B aligned
    const float  lw = rowp[max(gx - 1, 0)];             // branchless clamp
    const float  rx = rowp[min(gx + 4, W - 1)];
    w6[0] = lw;  w6[1] = M.x; w6[2] = M.y; w6[3] = M.z; w6[4] = M.w;
    w6[5] = rx;
}

__global__ __launch_bounds__(256)
void bilat_direct(const float* __restrict__ in, float* __restrict__ out,
                  const float* __restrict__ sxyz, const float* __restrict__ srr,
                  int p, int H, int W)
{
    const int tid = threadIdx.x;
    const int q = tid & 15;           // quad 0..15
    const int r = tid >> 4;           // row  0..15
    const int gx = blockIdx.x * DTX + 4 * q;
    const int gy = blockIdx.y * DTY + r;
    const size_t img_off = (size_t)blockIdx.z * (size_t)H * (size_t)W;
    const float* __restrict__ img = in + img_off;

    const float L2E = 1.4426950408889634f;
    const float sx = sxyz[2 * p], sy = sxyz[2 * p + 1], sr = srr[p];
    const float ncr = -0.5f / (sr * sr) * L2E;
    const float nax = -0.5f / (sx * sx) * L2E;
    const float nay = -0.5f / (sy * sy) * L2E;
    const bool prune = (4.f * nax < TH2) && (4.f * nay < TH2);
    const v2f ncr2 = {ncr, ncr};

    float* op = out + img_off + (size_t)gy * W + gx;

    if (prune) {
        // rows gy-1, gy, gy+1 (replicate-clamped row bases, branchless)
        const float* rm = img + (size_t)max(gy - 1, 0)     * W;
        const float* rc = img + (size_t)gy                 * W;
        const float* rp = img + (size_t)min(gy + 1, H - 1) * W;
        float wm[6], wc[6], wp[6];
        ld6(rm, gx, W, wm);                 // 9 independent loads total
        ld6(rc, gx, W, wc);
        ld6(rp, gx, W, wp);
        *(float4*)op = core3x3(wm, wc, wp, nax, nay, ncr2);
    } else {
        // ---- generic 5x5, streaming per row (cold path) ----
        const float4 C = *(const float4*)(img + (size_t)gy * W + gx);
        float cen[4] = {C.x, C.y, C.z, C.w};
        float num[4] = {C.x, C.y, C.z, C.w};
        float den[4] = {1.f, 1.f, 1.f, 1.f};
        #pragma unroll
        for (int dr = -2; dr <= 2; ++dr) {
            const float ra = (float)(dr * dr) * nax;
            const float rbest = dr ? ra : nay;
            if (rbest < TH2) continue;
            const float* rp2 = img + (size_t)min(max(gy + dr, 0), H - 1) * W;
            const float4 Mq = *(const float4*)(rp2 + gx);
            const float w8[8] = {
                rp2[max(gx - 2, 0)], rp2[max(gx - 1, 0)],
                Mq.x, Mq.y, Mq.z, Mq.w,
                rp2[min(gx + 4, W - 1)], rp2[min(gx + 5, W - 1)]};
            #pragma unroll
            for (int dc = -2; dc <= 2; ++dc) {
                if (dr == 0 && dc == 0) continue;
                const float b = ra + (float)(dc * dc) * nay;
                if (b < TH2) continue;
                #pragma unroll
                for (int j = 0; j < 4; ++j) {
                    const float nb = w8[2 + j + dc];
                    const float d  = nb - cen[j];
                    const float tt = fmaf(d * d, ncr, b);
                    const float w  = EXP2(tt);
                    num[j] = fmaf(w, nb, num[j]);
                    den[j] += w;
                }
            }
        }
        float4 o;
        o.x = num[0] * RCP(den[0]);
        o.y = num[1] * RCP(den[1]);
        o.z = num[2] * RCP(den[2]);
        o.w = num[3] * RCP(den[3]);
        *(float4*)op = o;
    }
}

// =======================================================================
// Fallback: fused 3-pass LDS kernel (rounds 9-11) if ws too small.
// =======================================================================

#define TILE_X 64
#define TILE_Y 32
#define S0R 44
#define S0C 92
#define S1R 40
#define S1C 84
#define S2R 36
#define S2C 76

__device__ __forceinline__ void mkrow6(const float* p, float* w6)
{
    const float4 L = *(const float4*)(p - 4);
    const float4 M = *(const float4*)(p);
    const float4 R = *(const float4*)(p + 4);
    w6[0] = L.w; w6[1] = M.x; w6[2] = M.y; w6[3] = M.z; w6[4] = M.w;
    w6[5] = R.x;
}

template<int NR, int NC>
__device__ __forceinline__ void replicate_fill(float* buf, int rlo, int rhi,
                                               int vlo, int vhi, int tid)
{
    if (rlo == 0 && vlo == 0 && rhi == NR - 1 && vhi == NC - 1) return;
    for (int t = tid; t < NR * NC; t += 256) {
        const int r = t / NC, v = t - r * NC;
        const int rs = min(max(r, rlo), rhi);
        const int vs = min(max(v, vlo), vhi);
        if (rs != r || vs != v) buf[r * NC + v] = buf[rs * NC + vs];
    }
}

template<int NQ, int NRH, int SST, int DSTST, bool TOG>
__device__ __forceinline__ void bilat_tile_pass(
    const float* __restrict__ src, float* __restrict__ dst,
    float* __restrict__ gout, int W,
    int tid, float ncr, float nax, float nay, bool prune)
{
    const v2f ncr2 = {ncr, ncr};
    for (int t = tid; t < NQ * NRH; t += 256) {
        const int rp = t / NQ;
        const int q  = t - rp * NQ;
        const int r0 = 2 * rp;
        const float* cp = src + (r0 + 2) * SST + 4 * q + 4;

        if (prune) {
            float w0[6], w1[6], w2[6], w3[6];
            mkrow6(cp - SST,     w0);
            mkrow6(cp,           w1);
            mkrow6(cp + SST,     w2);
            mkrow6(cp + 2 * SST, w3);
            const float4 oA = core3x3(w0, w1, w2, nax, nay, ncr2);
            const float4 oB = core3x3(w1, w2, w3, nax, nay, ncr2);
            if (TOG) {
                *(float4*)(gout + (r0    ) * W + 4 * q) = oA;
                *(float4*)(gout + (r0 + 1) * W + 4 * q) = oB;
            } else {
                *(float4*)(dst + (r0    ) * DSTST + 4 * q) = oA;
                *(float4*)(dst + (r0 + 1) * DSTST + 4 * q) = oB;
            }
        } else {
            #pragma unroll
            for (int rr = 0; rr < 2; ++rr) {
                const float* cp2 = cp + rr * SST;
                const float4 M0 = *(const float4*)cp2;
                float cen[4] = {M0.x, M0.y, M0.z, M0.w};
                float num[4] = {M0.x, M0.y, M0.z, M0.w};
                float den[4] = {1.f, 1.f, 1.f, 1.f};
                #pragma unroll
                for (int dr = -2; dr <= 2; ++dr) {
                    const float ra = (float)(dr * dr) * nax;
                    const float rbest = dr ? ra : nay;
                    if (rbest < TH2) continue;
                    const float* rp2 = cp2 + dr * SST;
                    const float4 Lq = *(const float4*)(rp2 - 4);
                    const float4 Mq = *(const float4*)(rp2);
                    const float4 Rq = *(const float4*)(rp2 + 4);
                    const float w8[8] = {Lq.z, Lq.w, Mq.x, Mq.y, Mq.z, Mq.w,
                                         Rq.x, Rq.y};
                    #pragma unroll
                    for (int dc = -2; dc <= 2; ++dc) {
                        if (dr == 0 && dc == 0) continue;
                        const float b = ra + (float)(dc * dc) * nay;
                        if (b < TH2) continue;
                        #pragma unroll
                        for (int j = 0; j < 4; ++j) {
                            const float nb = w8[2 + j + dc];
                            const float d  = nb - cen[j];
                            const float tt = fmaf(d * d, ncr, b);
                            const float w  = EXP2(tt);
                            num[j] = fmaf(w, nb, num[j]);
                            den[j] += w;
                        }
                    }
                }
                float4 o;
                o.x = num[0] * RCP(den[0]);
                o.y = num[1] * RCP(den[1]);
                o.z = num[2] * RCP(den[2]);
                o.w = num[3] * RCP(den[3]);
                if (TOG) *(float4*)(gout + (r0 + rr) * W + 4 * q) = o;
                else     *(float4*)(dst + (r0 + rr) * DSTST + 4 * q) = o;
            }
        }
    }
}

template<int NR, int NC, int RO, int CO>
__device__ __forceinline__ void stage_aperture(const float* __restrict__ img,
                                               float* __restrict__ buf,
                                               int Y0, int X0, int H, int W,
                                               int tid)
{
    const int NQ = NC / 4;
    for (int t = tid; t < NR * NQ; t += 256) {
        const int r = t / NQ, k = t - r * NQ;
        const int gy = Y0 + RO + r;
        const int gx = X0 + CO + 4 * k;
        float4 v;
        if (gy >= 0 && gy < H && gx >= 0 && gx + 3 < W) {
            v = *(const float4*)(img + (size_t)gy * W + gx);
        } else {
            const size_t rb = (size_t)min(max(gy, 0), H - 1) * W;
            v.x = img[rb + min(max(gx    , 0), W - 1)];
            v.y = img[rb + min(max(gx + 1, 0), W - 1)];
            v.z = img[rb + min(max(gx + 2, 0), W - 1)];
            v.w = img[rb + min(max(gx + 3, 0), W - 1)];
        }
        *(float4*)(buf + r * NC + 4 * k) = v;
    }
}

__global__ __launch_bounds__(256)
void bilat3_fused(const float* __restrict__ in, float* __restrict__ out,
                  const float* __restrict__ sxyz, const float* __restrict__ srr,
                  int H, int W)
{
    __shared__ __align__(16) float buf0[S0R * S0C];
    __shared__ __align__(16) float buf1[S1R * S1C];

    const int tid = threadIdx.x;
    const int X0 = blockIdx.x * TILE_X;
    const int Y0 = blockIdx.y * TILE_Y;
    const size_t img_off = (size_t)blockIdx.z * (size_t)H * (size_t)W;

    const float L2E = 1.4426950408889634f;
    float ncr[3], nax[3], nay[3];
    bool prune[3];
    #pragma unroll
    for (int p = 0; p < 3; ++p) {
        const float sx = sxyz[2 * p], sy = sxyz[2 * p + 1], sr = srr[p];
        ncr[p] = -0.5f / (sr * sr) * L2E;
        nax[p] = -0.5f / (sx * sx) * L2E;
        nay[p] = -0.5f / (sy * sy) * L2E;
        prune[p] = (4.f * nax[p] < TH2) && (4.f * nay[p] < TH2);
    }

    stage_aperture<S0R, S0C, -6, -12>(in + img_off, buf0, Y0, X0, H, W, tid);
    __syncthreads();

    bilat_tile_pass<S1C / 4, S1R / 2, S0C, S1C, false>(
        buf0, buf1, nullptr, W, tid, ncr[0], nax[0], nay[0], prune[0]);
    __syncthreads();
    replicate_fill<S1R, S1C>(buf1,
        max(0, 4 - Y0), min(S1R - 1, (H - 1) - (Y0 - 4)),
        max(0, 8 - X0), min(S1C - 1, (W - 1) - (X0 - 8)), tid);
    __syncthreads();

    float* buf2 = buf0;
    bilat_tile_pass<S2C / 4, S2R / 2, S1C, S2C, false>(
        buf1, buf2, nullptr, W, tid, ncr[1], nax[1], nay[1], prune[1]);
    __syncthreads();
    replicate_fill<S2R, S2C>(buf2,
        max(0, 2 - Y0), min(S2R - 1, (H - 1) - (Y0 - 2)),
        max(0, 4 - X0), min(S2C - 1, (W - 1) - (X0 - 4)), tid);
    __syncthreads();

    float* gout = out + img_off + (size_t)Y0 * W + X0;
    bilat_tile_pass<TILE_X / 4, TILE_Y / 2, S2C, 0, true>(
        buf2, nullptr, gout, W, tid, ncr[2], nax[2], nay[2], prune[2]);
}

// =======================================================================

extern "C" void kernel_launch(void* const* d_in, const int* in_sizes, int n_in,
                              void* d_out, int out_size, void* d_ws, size_t ws_size,
                              hipStream_t stream)
{
    const float* x    = (const float*)d_in[0];
    const float* sxyz = (const float*)d_in[1];   // [3,2]
    const float* sr   = (const float*)d_in[2];   // [3]
    float* out = (float*)d_out;

    const int H = 512, W = 512;
    const int BC = in_sizes[0] / (H * W);        // 32

    const size_t img_bytes = (size_t)BC * H * W * sizeof(float);
    if (d_ws && ws_size >= img_bytes) {
        float* ws = (float*)d_ws;
        dim3 block(256);
        dim3 grid(W / DTX, H / DTY, BC);         // 8 x 32 x 32 = 8192 blocks
        // pass 1: in -> out, pass 2: out -> ws, pass 3: ws -> out
        bilat_direct<<<grid, block, 0, stream>>>(x,   out, sxyz, sr, 0, H, W);
        bilat_direct<<<grid, block, 0, stream>>>(out, ws,  sxyz, sr, 1, H, W);
        bilat_direct<<<grid, block, 0, stream>>>(ws,  out, sxyz, sr, 2, H, W);
    } else {
        dim3 block(256);
        dim3 grid(W / TILE_X, H / TILE_Y, BC);   // 8 x 16 x 32 = 4096 blocks
        bilat3_fused<<<grid, block, 0, stream>>>(x, out, sxyz, sr, H, W);
    }
}